// Round 3
// baseline (457.373 us; speedup 1.0000x reference)
//
#include <hip/hip_runtime.h>
#include <hip/hip_fp16.h>

#define P_PLANE (1080*1920)          // 2,073,600 pixels per channel plane
#define LUT_C   35937                 // 33*33*33, per-channel LUT stride
#define N_IMG   4
#define SMEM_WORDS 35937
#define SMEM_BYTES (SMEM_WORDS * 4)   // 143,748 B of LDS (legacy path)

#define N_CELLS   32768               // 32*32*32 interpolation cells
#define CELL_BYTES 32                 // 8 corners x u8x4 dword
#define TABLE_BYTES ((size_t)N_CELLS * CELL_BYTES)   // 1 MB

typedef float fvec4 __attribute__((ext_vector_type(4)));   // builtin-compatible float4

__device__ __forceinline__ float ub0(unsigned int e) { return (float)(e & 255u); }
__device__ __forceinline__ float ub1(unsigned int e) { return (float)((e >> 8) & 255u); }
__device__ __forceinline__ float ub2(unsigned int e) { return (float)((e >> 16) & 255u); }

// ---------------------------------------------------------------------------
// R3 table: cell-duplicated u8. Cell c = (bi<<10)|(gi<<5)|ri holds its 8
// corners as 8 packed (r,g,b,0) u8 dwords = one 32B half-cacheline.
// Corner k order: bit0=dr, bit1=dg, bit2=db  ->  e000,e001,e010,...,e111
// (identical value + ordering semantics to the proven LDS-u8 path).
// ---------------------------------------------------------------------------
__global__ __launch_bounds__(256) void build_cell_u8(const float* __restrict__ lut,
                                                     uint4* __restrict__ T) {
    int c = blockIdx.x * blockDim.x + threadIdx.x;
    if (c >= N_CELLS) return;
    int ri = c & 31, gi = (c >> 5) & 31, bi = c >> 10;
    int idx = bi * 1089 + gi * 33 + ri;
    unsigned int w[8];
#pragma unroll
    for (int k = 0; k < 8; ++k) {
        int off = idx + (k & 1) + ((k >> 1) & 1) * 33 + ((k >> 2) & 1) * 1089;
        unsigned int r = (unsigned int)__float2int_rn(lut[off] * 255.0f);
        unsigned int g = (unsigned int)__float2int_rn(lut[LUT_C + off] * 255.0f);
        unsigned int b = (unsigned int)__float2int_rn(lut[2 * LUT_C + off] * 255.0f);
        w[k] = r | (g << 8) | (b << 16);
    }
    T[(size_t)c * 2]     = make_uint4(w[0], w[1], w[2], w[3]);
    T[(size_t)c * 2 + 1] = make_uint4(w[4], w[5], w[6], w[7]);
}

// ---------------------------------------------------------------------------
// R3 main kernel: no LDS. Per pixel: one 64B-line gather (2x dwordx4) from
// the 1MB L2-resident cell table. __launch_bounds__(256,8) -> <=64 VGPR ->
// 8 waves/SIMD (2x the LDS path's occupancy cap); 2048 blocks load-balance.
// Arithmetic is bit-identical to the LDS-u8 path.
// ---------------------------------------------------------------------------
__global__ __launch_bounds__(256, 8) void apply_lut_cell(const float* __restrict__ x,
                                                         const uint4* __restrict__ T,
                                                         float* __restrict__ out) {
    const float inv = (float)(1.0 / (1.000001 / 32.0));   // matches reference f32 rounding
    const float qs = 1.0f / 255.0f;                        // u8 dequant, folded into wb
    const int QPI = P_PLANE / 4;                           // 518,400 quads per image
    const int total = N_IMG * QPI;                         // 2,073,600 quads
    const int stride = gridDim.x * blockDim.x;

    for (int q = blockIdx.x * blockDim.x + threadIdx.x; q < total; q += stride) {
        int n = q / QPI;
        size_t base = (size_t)n * (3 * P_PLANE) + (size_t)(q - n * QPI) * 4;

        fvec4 r4 = *(const fvec4*)(x + base);
        fvec4 g4 = *(const fvec4*)(x + base + P_PLANE);
        fvec4 b4 = *(const fvec4*)(x + base + 2 * P_PLANE);

        fvec4 vR, vG, vB;

#pragma unroll
        for (int i = 0; i < 4; ++i) {
            float tr = r4[i] * inv;
            float tg = g4[i] * inv;
            float tb = b4[i] * inv;
            float fr_ = floorf(tr), fg_ = floorf(tg), fb_ = floorf(tb);
            float fr = tr - fr_, fg = tg - fg_, fb = tb - fb_;   // fracs BEFORE clip
            int ri = min(max((int)fr_, 0), 31);
            int gi = min(max((int)fg_, 0), 31);
            int bi = min(max((int)fb_, 0), 31);
            int c = (bi << 10) | (gi << 5) | ri;

            const uint4* cp = T + (size_t)c * 2;
            uint4 lo = cp[0];            // e000,e001,e010,e011
            uint4 hi = cp[1];            // e100,e101,e110,e111

            float wr1 = fr, wr0 = 1.0f - fr;
            float wg1 = fg, wg0 = 1.0f - fg;
            float wb1 = fb * qs, wb0 = (1.0f - fb) * qs;   // fold 1/255 here
            float w00 = wb0 * wg0, w01 = wb0 * wg1, w10 = wb1 * wg0, w11 = wb1 * wg1;
            float w000 = w00 * wr0, w001 = w00 * wr1;
            float w010 = w01 * wr0, w011 = w01 * wr1;
            float w100 = w10 * wr0, w101 = w10 * wr1;
            float w110 = w11 * wr0, w111 = w11 * wr1;

            float aR = w000 * ub0(lo.x);
            float aG = w000 * ub1(lo.x);
            float aB = w000 * ub2(lo.x);
            aR = fmaf(w001, ub0(lo.y), aR); aG = fmaf(w001, ub1(lo.y), aG); aB = fmaf(w001, ub2(lo.y), aB);
            aR = fmaf(w010, ub0(lo.z), aR); aG = fmaf(w010, ub1(lo.z), aG); aB = fmaf(w010, ub2(lo.z), aB);
            aR = fmaf(w011, ub0(lo.w), aR); aG = fmaf(w011, ub1(lo.w), aG); aB = fmaf(w011, ub2(lo.w), aB);
            aR = fmaf(w100, ub0(hi.x), aR); aG = fmaf(w100, ub1(hi.x), aG); aB = fmaf(w100, ub2(hi.x), aB);
            aR = fmaf(w101, ub0(hi.y), aR); aG = fmaf(w101, ub1(hi.y), aG); aB = fmaf(w101, ub2(hi.y), aB);
            aR = fmaf(w110, ub0(hi.z), aR); aG = fmaf(w110, ub1(hi.z), aG); aB = fmaf(w110, ub2(hi.z), aB);
            aR = fmaf(w111, ub0(hi.w), aR); aG = fmaf(w111, ub1(hi.w), aG); aB = fmaf(w111, ub2(hi.w), aB);

            vR[i] = aR; vG[i] = aG; vB[i] = aB;
        }

        __builtin_nontemporal_store(vR, (fvec4*)(out + base));
        __builtin_nontemporal_store(vG, (fvec4*)(out + base + P_PLANE));
        __builtin_nontemporal_store(vB, (fvec4*)(out + base + 2 * P_PLANE));
    }
}

// ===========================================================================
// Legacy primary (R2, proven 63us): full LUT (u8x4) resident in LDS.
// Kept as dispatch fallback.
// ===========================================================================
__global__ __launch_bounds__(256) void build_lin_u8(const float* __restrict__ lut,
                                                    unsigned int* __restrict__ T) {
    int i = blockIdx.x * blockDim.x + threadIdx.x;
    if (i >= LUT_C) return;
    unsigned int r = (unsigned int)__float2int_rn(lut[i] * 255.0f);
    unsigned int g = (unsigned int)__float2int_rn(lut[LUT_C + i] * 255.0f);
    unsigned int b = (unsigned int)__float2int_rn(lut[2 * LUT_C + i] * 255.0f);
    T[i] = r | (g << 8) | (b << 16);
}

__global__ __launch_bounds__(1024, 4) void apply_lut_lds(const float* __restrict__ x,
                                                         const unsigned int* __restrict__ T,
                                                         float* __restrict__ out) {
    extern __shared__ unsigned int s_lut[];
    const int tid = threadIdx.x;
    {
        const uint4* Tv = (const uint4*)T;
        uint4* sv = (uint4*)s_lut;
        for (int i = tid; i < SMEM_WORDS / 4; i += blockDim.x) sv[i] = Tv[i];
        if (tid == 0) s_lut[SMEM_WORDS - 1] = T[SMEM_WORDS - 1];
    }
    __syncthreads();

    const float inv = (float)(1.0 / (1.000001 / 32.0));
    const float qs = 1.0f / 255.0f;
    const int QPI = P_PLANE / 4;
    const int total = N_IMG * QPI;

    for (int q = blockIdx.x * blockDim.x + tid; q < total; q += gridDim.x * blockDim.x) {
        int n = q / QPI;
        size_t base = (size_t)n * (3 * P_PLANE) + (size_t)(q - n * QPI) * 4;

        fvec4 r4 = *(const fvec4*)(x + base);
        fvec4 g4 = *(const fvec4*)(x + base + P_PLANE);
        fvec4 b4 = *(const fvec4*)(x + base + 2 * P_PLANE);
        fvec4 vR, vG, vB;

#pragma unroll
        for (int i = 0; i < 4; ++i) {
            float tr = r4[i] * inv, tg = g4[i] * inv, tb = b4[i] * inv;
            float fr_ = floorf(tr), fg_ = floorf(tg), fb_ = floorf(tb);
            float fr = tr - fr_, fg = tg - fg_, fb = tb - fb_;
            int ri = min(max((int)fr_, 0), 31);
            int gi = min(max((int)fg_, 0), 31);
            int bi = min(max((int)fb_, 0), 31);
            int idx = bi * 1089 + gi * 33 + ri;

            unsigned int e000 = s_lut[idx],        e001 = s_lut[idx + 1];
            unsigned int e010 = s_lut[idx + 33],   e011 = s_lut[idx + 34];
            unsigned int e100 = s_lut[idx + 1089], e101 = s_lut[idx + 1090];
            unsigned int e110 = s_lut[idx + 1122], e111 = s_lut[idx + 1123];

            float wr1 = fr, wr0 = 1.0f - fr;
            float wg1 = fg, wg0 = 1.0f - fg;
            float wb1 = fb * qs, wb0 = (1.0f - fb) * qs;
            float w00 = wb0 * wg0, w01 = wb0 * wg1, w10 = wb1 * wg0, w11 = wb1 * wg1;
            float w000 = w00 * wr0, w001 = w00 * wr1;
            float w010 = w01 * wr0, w011 = w01 * wr1;
            float w100 = w10 * wr0, w101 = w10 * wr1;
            float w110 = w11 * wr0, w111 = w11 * wr1;

            float aR = w000 * ub0(e000), aG = w000 * ub1(e000), aB = w000 * ub2(e000);
            aR = fmaf(w001, ub0(e001), aR); aG = fmaf(w001, ub1(e001), aG); aB = fmaf(w001, ub2(e001), aB);
            aR = fmaf(w010, ub0(e010), aR); aG = fmaf(w010, ub1(e010), aG); aB = fmaf(w010, ub2(e010), aB);
            aR = fmaf(w011, ub0(e011), aR); aG = fmaf(w011, ub1(e011), aG); aB = fmaf(w011, ub2(e011), aB);
            aR = fmaf(w100, ub0(e100), aR); aG = fmaf(w100, ub1(e100), aG); aB = fmaf(w100, ub2(e100), aB);
            aR = fmaf(w101, ub0(e101), aR); aG = fmaf(w101, ub1(e101), aG); aB = fmaf(w101, ub2(e101), aB);
            aR = fmaf(w110, ub0(e110), aR); aG = fmaf(w110, ub1(e110), aG); aB = fmaf(w110, ub2(e110), aB);
            aR = fmaf(w111, ub0(e111), aR); aG = fmaf(w111, ub1(e111), aG); aB = fmaf(w111, ub2(e111), aB);

            vR[i] = aR; vG[i] = aG; vB[i] = aB;
        }

        __builtin_nontemporal_store(vR, (fvec4*)(out + base));
        __builtin_nontemporal_store(vG, (fvec4*)(out + base + P_PLANE));
        __builtin_nontemporal_store(vB, (fvec4*)(out + base + 2 * P_PLANE));
    }
}

extern "C" void kernel_launch(void* const* d_in, const int* in_sizes, int n_in,
                              void* d_out, int out_size, void* d_ws, size_t ws_size,
                              hipStream_t stream) {
    const float* lut = (const float*)d_in[0];
    const float* x   = (const float*)d_in[1];
    float* out = (float*)d_out;

    static int max_shm = -1;
    if (max_shm < 0) {
        int dev = 0;
        (void)hipGetDevice(&dev);
        (void)hipDeviceGetAttribute(&max_shm, hipDeviceAttributeMaxSharedMemoryPerBlock, dev);
        static_assert(SMEM_BYTES == 143748, "lut lds size");
        (void)hipFuncSetAttribute((const void*)apply_lut_lds,
                                  hipFuncAttributeMaxDynamicSharedMemorySize, SMEM_BYTES);
        if (max_shm < 0) max_shm = 0;
    }

    if (ws_size >= TABLE_BYTES) {
        // R3 path: 1MB cell-duplicated u8 table, L2-resident; no-LDS apply.
        uint4* T = (uint4*)d_ws;
        build_cell_u8<<<N_CELLS / 256, 256, 0, stream>>>(lut, T);
        apply_lut_cell<<<2048, 256, 0, stream>>>(x, T, out);
    } else if (max_shm >= SMEM_BYTES && ws_size >= (size_t)SMEM_BYTES) {
        // R2 path (proven 63us): LDS-resident linear u8 table.
        unsigned int* T = (unsigned int*)d_ws;
        build_lin_u8<<<(LUT_C + 255) / 256, 256, 0, stream>>>(lut, T);
        apply_lut_lds<<<256, 1024, SMEM_BYTES, stream>>>(x, T, out);
    }
}

// Round 4
// 187.628 us; speedup vs baseline: 2.4377x; 2.4377x over previous
//
#include <hip/hip_runtime.h>
#include <hip/hip_fp16.h>

#define P_PLANE (1080*1920)          // 2,073,600 pixels per channel plane
#define LUT_C   35937                 // 33*33*33, per-channel LUT stride
#define N_IMG   4
#define SMEM_WORDS 35937
#define SMEM_BYTES (SMEM_WORDS * 4)   // 143,748 B of LDS

typedef float fvec4 __attribute__((ext_vector_type(4)));   // builtin-compatible float4

__device__ __forceinline__ float ub0(unsigned int e) { return (float)(e & 255u); }
__device__ __forceinline__ float ub1(unsigned int e) { return (float)((e >> 8) & 255u); }
__device__ __forceinline__ float ub2(unsigned int e) { return (float)((e >> 16) & 255u); }

// ---------------------------------------------------------------------------
// Build linear u8 table in ws: entry i (= b*1089+g*33+r) packs (r,g,b,0) u8.
// 35937 entries * 4B = 140.4 KB. Quantization err <= 1/510 ~ 2e-3.
// ---------------------------------------------------------------------------
__global__ __launch_bounds__(256) void build_lin_u8(const float* __restrict__ lut,
                                                    unsigned int* __restrict__ T) {
    int i = blockIdx.x * blockDim.x + threadIdx.x;
    if (i >= LUT_C) return;
    unsigned int r = (unsigned int)__float2int_rn(lut[i] * 255.0f);
    unsigned int g = (unsigned int)__float2int_rn(lut[LUT_C + i] * 255.0f);
    unsigned int b = (unsigned int)__float2int_rn(lut[2 * LUT_C + i] * 255.0f);
    T[i] = r | (g << 8) | (b << 16);
}

// ---------------------------------------------------------------------------
// R4 main kernel: full LUT (u8x4) in LDS (proven structure, R2 = 63.5us),
// plus an EXPLICIT cross-iteration software pipeline to break the 16-wave
// convoy (R2's VGPR=48 showed the compiler never prefetched):
//   per iteration: idx/frac -> issue 16 ds_read2 gathers -> issue NEXT
//   iteration's 6 global loads -> weights (independent of gathers) ->
//   FMA (absorbs lgkmcnt wait) -> stores (absorb vmcnt wait).
// One quad (4 px) per iteration keeps peak live VGPR ~90 < 128 so the
// 1024-thread block (16 waves, LDS-capped 1 block/CU) still launches.
// ---------------------------------------------------------------------------
__global__ __launch_bounds__(1024, 4) void apply_lut_lds(const float* __restrict__ x,
                                                         const unsigned int* __restrict__ T,
                                                         float* __restrict__ out) {
    extern __shared__ unsigned int s_lut[];
    const int tid = threadIdx.x;

    // Fill LDS: 8984 uint4 + 1 tail word, coalesced.
    {
        const uint4* Tv = (const uint4*)T;
        uint4* sv = (uint4*)s_lut;
        for (int i = tid; i < SMEM_WORDS / 4; i += blockDim.x) sv[i] = Tv[i];
        if (tid == 0) s_lut[SMEM_WORDS - 1] = T[SMEM_WORDS - 1];
    }
    __syncthreads();

    const float inv = (float)(1.0 / (1.000001 / 32.0));   // matches reference f32 rounding
    const float qs = 1.0f / 255.0f;                        // u8 dequant, folded into wb
    const int QPI = P_PLANE / 4;                           // 518,400 quads per image
    const int total = N_IMG * QPI;                         // 2,073,600 quads
    const int G = gridDim.x * blockDim.x;                  // 262,144

    int q = blockIdx.x * blockDim.x + tid;
    if (q >= total) return;

    // ---- Prologue: loads for the first iteration.
    size_t base;
    {
        int n = q / QPI;
        base = (size_t)n * (3 * P_PLANE) + (size_t)(q - n * QPI) * 4;
    }
    fvec4 r4 = *(const fvec4*)(x + base);
    fvec4 g4 = *(const fvec4*)(x + base + P_PLANE);
    fvec4 b4 = *(const fvec4*)(x + base + 2 * P_PLANE);

    while (true) {
        // ---- Phase 1: idx + fracs for 4 pixels (consumes current loads).
        int   idx[4];
        float fr[4], fg[4], fb[4];
#pragma unroll
        for (int i = 0; i < 4; ++i) {
            float tr = r4[i] * inv, tg = g4[i] * inv, tb = b4[i] * inv;
            float fr_ = floorf(tr), fg_ = floorf(tg), fb_ = floorf(tb);
            fr[i] = tr - fr_; fg[i] = tg - fg_; fb[i] = tb - fb_;   // fracs BEFORE clip
            int ri = min(max((int)fr_, 0), 31);
            int gi = min(max((int)fg_, 0), 31);
            int bi = min(max((int)fb_, 0), 31);
            idx[i] = bi * 1089 + gi * 33 + ri;
        }

        // ---- Phase 2: issue all 16 ds_read2-class gathers (32 dwords).
        unsigned int e[4][8];
#pragma unroll
        for (int i = 0; i < 4; ++i) {
            int i0 = idx[i];
            int i1 = idx[i] + 1089;
            e[i][0] = s_lut[i0];       e[i][1] = s_lut[i0 + 1];
            e[i][2] = s_lut[i0 + 33];  e[i][3] = s_lut[i0 + 34];
            e[i][4] = s_lut[i1];       e[i][5] = s_lut[i1 + 1];
            e[i][6] = s_lut[i1 + 33];  e[i][7] = s_lut[i1 + 34];
        }

        // ---- Phase 3: issue NEXT iteration's global loads (longest latency;
        // covered by phases 4-6). Branchless: last iteration re-reads q (L1-hot).
        int qn = q + G;
        const bool more = (qn < total);
        int qc = more ? qn : q;
        size_t nbase;
        {
            int n = qc / QPI;
            nbase = (size_t)n * (3 * P_PLANE) + (size_t)(qc - n * QPI) * 4;
        }
        fvec4 nr4 = *(const fvec4*)(x + nbase);
        fvec4 ng4 = *(const fvec4*)(x + nbase + P_PLANE);
        fvec4 nb4 = *(const fvec4*)(x + nbase + 2 * P_PLANE);

        // ---- Phase 4: weights (independent of the LDS gathers — fills the
        // lgkmcnt shadow).
        float w[4][8];
#pragma unroll
        for (int i = 0; i < 4; ++i) {
            float wr1 = fr[i], wr0 = 1.0f - fr[i];
            float wg1 = fg[i], wg0 = 1.0f - fg[i];
            float wb1 = fb[i] * qs, wb0 = (1.0f - fb[i]) * qs;   // fold 1/255
            float w00 = wb0 * wg0, w01 = wb0 * wg1, w10 = wb1 * wg0, w11 = wb1 * wg1;
            w[i][0] = w00 * wr0; w[i][1] = w00 * wr1;
            w[i][2] = w01 * wr0; w[i][3] = w01 * wr1;
            w[i][4] = w10 * wr0; w[i][5] = w10 * wr1;
            w[i][6] = w11 * wr0; w[i][7] = w11 * wr1;
        }

        // ---- Phase 5: interpolate (first use of e[] -> lgkm wait lands here).
        fvec4 vR, vG, vB;
#pragma unroll
        for (int i = 0; i < 4; ++i) {
            float aR = w[i][0] * ub0(e[i][0]);
            float aG = w[i][0] * ub1(e[i][0]);
            float aB = w[i][0] * ub2(e[i][0]);
#pragma unroll
            for (int k = 1; k < 8; ++k) {
                aR = fmaf(w[i][k], ub0(e[i][k]), aR);
                aG = fmaf(w[i][k], ub1(e[i][k]), aG);
                aB = fmaf(w[i][k], ub2(e[i][k]), aB);
            }
            vR[i] = aR; vG[i] = aG; vB[i] = aB;
        }

        // ---- Phase 6: coalesced nontemporal stores (1KB/wave each).
        __builtin_nontemporal_store(vR, (fvec4*)(out + base));
        __builtin_nontemporal_store(vG, (fvec4*)(out + base + P_PLANE));
        __builtin_nontemporal_store(vB, (fvec4*)(out + base + 2 * P_PLANE));

        if (!more) break;
        q = qn; base = nbase;
        r4 = nr4; g4 = ng4; b4 = nb4;   // vmcnt wait for these was covered by 4-6
    }
}

// ===========================================================================
// Fallback path (R0, proven): fp16 cell-duplicated table + global gathers.
// ===========================================================================
__global__ __launch_bounds__(256) void build_table(const float* __restrict__ lut,
                                                   uint4* __restrict__ T) {
    int cell = blockIdx.x * blockDim.x + threadIdx.x;   // 0 .. 32767
    int rid = cell & 31;
    int gid = (cell >> 5) & 31;
    int bid = cell >> 10;
    const float* b0 = lut + bid * 1089 + gid * 33 + rid;
    uint4 q[4];
    __half* h = (__half*)q;
#pragma unroll
    for (int k = 0; k < 8; ++k) {
        int off = (k >> 2) * 1089 + ((k >> 1) & 1) * 33 + (k & 1);
        h[k * 4 + 0] = __float2half(b0[off]);
        h[k * 4 + 1] = __float2half(b0[LUT_C + off]);
        h[k * 4 + 2] = __float2half(b0[2 * LUT_C + off]);
        h[k * 4 + 3] = __float2half(0.0f);
    }
    uint4* dst = T + (size_t)cell * 4;
    dst[0] = q[0]; dst[1] = q[1]; dst[2] = q[2]; dst[3] = q[3];
}

__device__ __forceinline__ void acc_chunk(const uint4& q, float wA, float wB,
                                          float& aR, float& aG, float& aB) {
    const __half* h = (const __half*)&q;
    aR = fmaf(wA, __half2float(h[0]), fmaf(wB, __half2float(h[4]), aR));
    aG = fmaf(wA, __half2float(h[1]), fmaf(wB, __half2float(h[5]), aG));
    aB = fmaf(wA, __half2float(h[2]), fmaf(wB, __half2float(h[6]), aB));
}

__global__ __launch_bounds__(256) void apply_lut(const float* __restrict__ x,
                                                 const __half* __restrict__ T,
                                                 float* __restrict__ out) {
    const float inv = (float)(1.0 / (1.000001 / 32.0));
    int n  = blockIdx.y;
    int i4 = blockIdx.x * blockDim.x + threadIdx.x;
    size_t base = (size_t)n * 3 * P_PLANE + (size_t)i4 * 4;

    float4 r4 = *(const float4*)(x + base);
    float4 g4 = *(const float4*)(x + base + P_PLANE);
    float4 b4 = *(const float4*)(x + base + 2 * P_PLANE);

    float r[4] = {r4.x, r4.y, r4.z, r4.w};
    float g[4] = {g4.x, g4.y, g4.z, g4.w};
    float b[4] = {b4.x, b4.y, b4.z, b4.w};
    float oR[4], oG[4], oB[4];

#pragma unroll
    for (int i = 0; i < 4; ++i) {
        float tr = r[i] * inv;
        float tg = g[i] * inv;
        float tb = b[i] * inv;
        float fr_ = floorf(tr), fg_ = floorf(tg), fb_ = floorf(tb);
        float fr = tr - fr_, fg = tg - fg_, fb = tb - fb_;
        int ri = min(max((int)fr_, 0), 31);
        int gi = min(max((int)fg_, 0), 31);
        int bi = min(max((int)fb_, 0), 31);

        const uint4* cp = (const uint4*)(T + ((size_t)(((bi << 5) | gi) << 5 | ri) << 5));
        uint4 q0 = cp[0], q1 = cp[1], q2 = cp[2], q3 = cp[3];

        float wr1 = fr, wr0 = 1.0f - fr;
        float wg1 = fg, wg0 = 1.0f - fg;
        float wb1 = fb, wb0 = 1.0f - fb;
        float w00 = wb0 * wg0, w01 = wb0 * wg1, w10 = wb1 * wg0, w11 = wb1 * wg1;

        float aR = 0.f, aG = 0.f, aB = 0.f;
        acc_chunk(q0, w00 * wr0, w00 * wr1, aR, aG, aB);
        acc_chunk(q1, w01 * wr0, w01 * wr1, aR, aG, aB);
        acc_chunk(q2, w10 * wr0, w10 * wr1, aR, aG, aB);
        acc_chunk(q3, w11 * wr0, w11 * wr1, aR, aG, aB);

        oR[i] = aR; oG[i] = aG; oB[i] = aB;
    }

    *(float4*)(out + base)               = make_float4(oR[0], oR[1], oR[2], oR[3]);
    *(float4*)(out + base + P_PLANE)     = make_float4(oG[0], oG[1], oG[2], oG[3]);
    *(float4*)(out + base + 2 * P_PLANE) = make_float4(oB[0], oB[1], oB[2], oB[3]);
}

extern "C" void kernel_launch(void* const* d_in, const int* in_sizes, int n_in,
                              void* d_out, int out_size, void* d_ws, size_t ws_size,
                              hipStream_t stream) {
    const float* lut = (const float*)d_in[0];
    const float* x   = (const float*)d_in[1];
    float* out = (float*)d_out;

    // Capture-safe host-side queries — cached so repeated kernel_launch calls
    // don't pay the runtime-API cost per invocation.
    static int max_shm = -1;
    if (max_shm < 0) {
        int dev = 0;
        (void)hipGetDevice(&dev);
        (void)hipDeviceGetAttribute(&max_shm, hipDeviceAttributeMaxSharedMemoryPerBlock, dev);
        static_assert(SMEM_BYTES == 143748, "lut lds size");
        (void)hipFuncSetAttribute((const void*)apply_lut_lds,
                                  hipFuncAttributeMaxDynamicSharedMemorySize, SMEM_BYTES);
        if (max_shm < 0) max_shm = 0;
    }

    if (max_shm >= SMEM_BYTES && ws_size >= (size_t)SMEM_BYTES) {
        // LDS-resident linear u8 table; 256 persistent blocks x 1024 threads
        // (1 block/CU, LDS-capped), software-pipelined grid-stride loop.
        unsigned int* T = (unsigned int*)d_ws;
        build_lin_u8<<<(LUT_C + 255) / 256, 256, 0, stream>>>(lut, T);
        apply_lut_lds<<<256, 1024, SMEM_BYTES, stream>>>(x, T, out);
    } else {
        __half* T = (__half*)d_ws;
        build_table<<<128, 256, 0, stream>>>(lut, (uint4*)T);
        apply_lut<<<dim3(P_PLANE / (4 * 256), N_IMG), 256, 0, stream>>>(x, T, out);
    }
}

// Round 5
// 186.145 us; speedup vs baseline: 2.4571x; 1.0080x over previous
//
#include <hip/hip_runtime.h>
#include <hip/hip_fp16.h>

#define P_PLANE (1080*1920)          // 2,073,600 pixels per channel plane
#define LUT_C   35937                 // 33*33*33, per-channel LUT stride
#define N_IMG   4
#define SMEM_WORDS 35937
#define SMEM_BYTES (SMEM_WORDS * 4)   // 143,748 B of LDS

typedef float fvec4 __attribute__((ext_vector_type(4)));   // builtin-compatible float4

__device__ __forceinline__ float ub0(unsigned int e) { return (float)(e & 255u); }
__device__ __forceinline__ float ub1(unsigned int e) { return (float)((e >> 8) & 255u); }
__device__ __forceinline__ float ub2(unsigned int e) { return (float)((e >> 16) & 255u); }

// ---------------------------------------------------------------------------
// Build linear u8 table in ws: entry i (= b*1089+g*33+r) packs (r,g,b,0) u8.
// 35937 entries * 4B = 140.4 KB. Quantization err <= 1/510 ~ 2e-3.
// ---------------------------------------------------------------------------
__global__ __launch_bounds__(256) void build_lin_u8(const float* __restrict__ lut,
                                                    unsigned int* __restrict__ T) {
    int i = blockIdx.x * blockDim.x + threadIdx.x;
    if (i >= LUT_C) return;
    unsigned int r = (unsigned int)__float2int_rn(lut[i] * 255.0f);
    unsigned int g = (unsigned int)__float2int_rn(lut[LUT_C + i] * 255.0f);
    unsigned int b = (unsigned int)__float2int_rn(lut[2 * LUT_C + i] * 255.0f);
    T[i] = r | (g << 8) | (b << 16);
}

// ---------------------------------------------------------------------------
// R5 main kernel: full LUT (u8x4) in LDS, with the phase structure PINNED by
// __builtin_amdgcn_sched_barrier(0).
// R2/R4 evidence: the compiler re-serializes source-level batching (VGPR
// stayed 40-48 despite e[4][8] in source), emitting gather-pair ->
// s_waitcnt lgkmcnt -> consume, i.e. ~8 exposed ~120cy LDS waits per
// iteration with only 4 waves/SIMD to cover them. The sched_barrier fence
// forbids the scheduler from sinking ds_reads past it / hoisting FMAs over
// it, forcing: all 16 ds_read2 issued -> (weights VALU in the DS shadow) ->
// ONE lgkmcnt wait -> 96 FMAs. Correctness is carried by data deps; the
// barrier only shapes scheduling.
// ---------------------------------------------------------------------------
__global__ __launch_bounds__(1024, 4) void apply_lut_lds(const float* __restrict__ x,
                                                         const unsigned int* __restrict__ T,
                                                         float* __restrict__ out) {
    extern __shared__ unsigned int s_lut[];
    const int tid = threadIdx.x;

    // Fill LDS: 8984 uint4 + 1 tail word, coalesced.
    {
        const uint4* Tv = (const uint4*)T;
        uint4* sv = (uint4*)s_lut;
        for (int i = tid; i < SMEM_WORDS / 4; i += blockDim.x) sv[i] = Tv[i];
        if (tid == 0) s_lut[SMEM_WORDS - 1] = T[SMEM_WORDS - 1];
    }
    __syncthreads();

    const float inv = (float)(1.0 / (1.000001 / 32.0));   // matches reference f32 rounding
    const float qs = 1.0f / 255.0f;                        // u8 dequant, folded into wb
    const int QPI = P_PLANE / 4;                           // 518,400 quads per image
    const int total = N_IMG * QPI;                         // 2,073,600 quads
    const int G = gridDim.x * blockDim.x;                  // 262,144

    int q = blockIdx.x * blockDim.x + tid;
    if (q >= total) return;

    size_t base;
    {
        int n = q / QPI;
        base = (size_t)n * (3 * P_PLANE) + (size_t)(q - n * QPI) * 4;
    }
    fvec4 r4 = *(const fvec4*)(x + base);
    fvec4 g4 = *(const fvec4*)(x + base + P_PLANE);
    fvec4 b4 = *(const fvec4*)(x + base + 2 * P_PLANE);

    while (true) {
        // ---- Phase A: idx + fracs for 4 pixels (consumes current loads).
        int   idx[4];
        float fr[4], fg[4], fb[4];
#pragma unroll
        for (int i = 0; i < 4; ++i) {
            float tr = r4[i] * inv, tg = g4[i] * inv, tb = b4[i] * inv;
            float fr_ = floorf(tr), fg_ = floorf(tg), fb_ = floorf(tb);
            fr[i] = tr - fr_; fg[i] = tg - fg_; fb[i] = tb - fb_;   // fracs BEFORE clip
            int ri = min(max((int)fr_, 0), 31);
            int gi = min(max((int)fg_, 0), 31);
            int bi = min(max((int)fb_, 0), 31);
            idx[i] = bi * 1089 + gi * 33 + ri;
        }

        // ---- Phase B: issue ALL 16 ds_read2-class gathers (32 dwords live).
        unsigned int e[4][8];
#pragma unroll
        for (int i = 0; i < 4; ++i) {
            int i0 = idx[i];
            int i1 = idx[i] + 1089;
            e[i][0] = s_lut[i0];       e[i][1] = s_lut[i0 + 1];
            e[i][2] = s_lut[i0 + 33];  e[i][3] = s_lut[i0 + 34];
            e[i][4] = s_lut[i1];       e[i][5] = s_lut[i1 + 1];
            e[i][6] = s_lut[i1 + 33];  e[i][7] = s_lut[i1 + 34];
        }

        // ---- Phase C: issue NEXT iteration's global loads (in the DS shadow).
        int qn = q + G;
        const bool more = (qn < total);
        int qc = more ? qn : q;                 // branchless tail: re-read q (L1-hot)
        size_t nbase;
        {
            int n = qc / QPI;
            nbase = (size_t)n * (3 * P_PLANE) + (size_t)(qc - n * QPI) * 4;
        }
        fvec4 nr4 = *(const fvec4*)(x + nbase);
        fvec4 ng4 = *(const fvec4*)(x + nbase + P_PLANE);
        fvec4 nb4 = *(const fvec4*)(x + nbase + 2 * P_PLANE);

        // ---- FENCE: nothing above may sink below; nothing below may hoist above.
        __builtin_amdgcn_sched_barrier(0);

        // ---- Phase D: weights (pure VALU, no e[] deps -> executes while the
        // DS pipe drains; the single lgkmcnt wait lands at Phase E's first use).
        float w[4][8];
#pragma unroll
        for (int i = 0; i < 4; ++i) {
            float wr1 = fr[i], wr0 = 1.0f - fr[i];
            float wg1 = fg[i], wg0 = 1.0f - fg[i];
            float wb1 = fb[i] * qs, wb0 = (1.0f - fb[i]) * qs;   // fold 1/255
            float w00 = wb0 * wg0, w01 = wb0 * wg1, w10 = wb1 * wg0, w11 = wb1 * wg1;
            w[i][0] = w00 * wr0; w[i][1] = w00 * wr1;
            w[i][2] = w01 * wr0; w[i][3] = w01 * wr1;
            w[i][4] = w10 * wr0; w[i][5] = w10 * wr1;
            w[i][6] = w11 * wr0; w[i][7] = w11 * wr1;
        }

        // ---- Phase E: interpolate (ONE lgkm wait, then 96 FMAs).
        fvec4 vR, vG, vB;
#pragma unroll
        for (int i = 0; i < 4; ++i) {
            float aR = w[i][0] * ub0(e[i][0]);
            float aG = w[i][0] * ub1(e[i][0]);
            float aB = w[i][0] * ub2(e[i][0]);
#pragma unroll
            for (int k = 1; k < 8; ++k) {
                aR = fmaf(w[i][k], ub0(e[i][k]), aR);
                aG = fmaf(w[i][k], ub1(e[i][k]), aG);
                aB = fmaf(w[i][k], ub2(e[i][k]), aB);
            }
            vR[i] = aR; vG[i] = aG; vB[i] = aB;
        }

        // ---- Phase F: coalesced nontemporal stores (1KB/wave each).
        __builtin_nontemporal_store(vR, (fvec4*)(out + base));
        __builtin_nontemporal_store(vG, (fvec4*)(out + base + P_PLANE));
        __builtin_nontemporal_store(vB, (fvec4*)(out + base + 2 * P_PLANE));

        if (!more) break;
        q = qn; base = nbase;
        r4 = nr4; g4 = ng4; b4 = nb4;
    }
}

// ===========================================================================
// Fallback path (R0, proven): fp16 cell-duplicated table + global gathers.
// ===========================================================================
__global__ __launch_bounds__(256) void build_table(const float* __restrict__ lut,
                                                   uint4* __restrict__ T) {
    int cell = blockIdx.x * blockDim.x + threadIdx.x;   // 0 .. 32767
    int rid = cell & 31;
    int gid = (cell >> 5) & 31;
    int bid = cell >> 10;
    const float* b0 = lut + bid * 1089 + gid * 33 + rid;
    uint4 q[4];
    __half* h = (__half*)q;
#pragma unroll
    for (int k = 0; k < 8; ++k) {
        int off = (k >> 2) * 1089 + ((k >> 1) & 1) * 33 + (k & 1);
        h[k * 4 + 0] = __float2half(b0[off]);
        h[k * 4 + 1] = __float2half(b0[LUT_C + off]);
        h[k * 4 + 2] = __float2half(b0[2 * LUT_C + off]);
        h[k * 4 + 3] = __float2half(0.0f);
    }
    uint4* dst = T + (size_t)cell * 4;
    dst[0] = q[0]; dst[1] = q[1]; dst[2] = q[2]; dst[3] = q[3];
}

__device__ __forceinline__ void acc_chunk(const uint4& q, float wA, float wB,
                                          float& aR, float& aG, float& aB) {
    const __half* h = (const __half*)&q;
    aR = fmaf(wA, __half2float(h[0]), fmaf(wB, __half2float(h[4]), aR));
    aG = fmaf(wA, __half2float(h[1]), fmaf(wB, __half2float(h[5]), aG));
    aB = fmaf(wA, __half2float(h[2]), fmaf(wB, __half2float(h[6]), aB));
}

__global__ __launch_bounds__(256) void apply_lut(const float* __restrict__ x,
                                                 const __half* __restrict__ T,
                                                 float* __restrict__ out) {
    const float inv = (float)(1.0 / (1.000001 / 32.0));
    int n  = blockIdx.y;
    int i4 = blockIdx.x * blockDim.x + threadIdx.x;
    size_t base = (size_t)n * 3 * P_PLANE + (size_t)i4 * 4;

    float4 r4 = *(const float4*)(x + base);
    float4 g4 = *(const float4*)(x + base + P_PLANE);
    float4 b4 = *(const float4*)(x + base + 2 * P_PLANE);

    float r[4] = {r4.x, r4.y, r4.z, r4.w};
    float g[4] = {g4.x, g4.y, g4.z, g4.w};
    float b[4] = {b4.x, b4.y, b4.z, b4.w};
    float oR[4], oG[4], oB[4];

#pragma unroll
    for (int i = 0; i < 4; ++i) {
        float tr = r[i] * inv;
        float tg = g[i] * inv;
        float tb = b[i] * inv;
        float fr_ = floorf(tr), fg_ = floorf(tg), fb_ = floorf(tb);
        float fr = tr - fr_, fg = tg - fg_, fb = tb - fb_;
        int ri = min(max((int)fr_, 0), 31);
        int gi = min(max((int)fg_, 0), 31);
        int bi = min(max((int)fb_, 0), 31);

        const uint4* cp = (const uint4*)(T + ((size_t)(((bi << 5) | gi) << 5 | ri) << 5));
        uint4 q0 = cp[0], q1 = cp[1], q2 = cp[2], q3 = cp[3];

        float wr1 = fr, wr0 = 1.0f - fr;
        float wg1 = fg, wg0 = 1.0f - fg;
        float wb1 = fb, wb0 = 1.0f - fb;
        float w00 = wb0 * wg0, w01 = wb0 * wg1, w10 = wb1 * wg0, w11 = wb1 * wg1;

        float aR = 0.f, aG = 0.f, aB = 0.f;
        acc_chunk(q0, w00 * wr0, w00 * wr1, aR, aG, aB);
        acc_chunk(q1, w01 * wr0, w01 * wr1, aR, aG, aB);
        acc_chunk(q2, w10 * wr0, w10 * wr1, aR, aG, aB);
        acc_chunk(q3, w11 * wr0, w11 * wr1, aR, aG, aB);

        oR[i] = aR; oG[i] = aG; oB[i] = aB;
    }

    *(float4*)(out + base)               = make_float4(oR[0], oR[1], oR[2], oR[3]);
    *(float4*)(out + base + P_PLANE)     = make_float4(oG[0], oG[1], oG[2], oG[3]);
    *(float4*)(out + base + 2 * P_PLANE) = make_float4(oB[0], oB[1], oB[2], oB[3]);
}

extern "C" void kernel_launch(void* const* d_in, const int* in_sizes, int n_in,
                              void* d_out, int out_size, void* d_ws, size_t ws_size,
                              hipStream_t stream) {
    const float* lut = (const float*)d_in[0];
    const float* x   = (const float*)d_in[1];
    float* out = (float*)d_out;

    // Capture-safe host-side queries — cached so repeated kernel_launch calls
    // don't pay the runtime-API cost per invocation.
    static int max_shm = -1;
    if (max_shm < 0) {
        int dev = 0;
        (void)hipGetDevice(&dev);
        (void)hipDeviceGetAttribute(&max_shm, hipDeviceAttributeMaxSharedMemoryPerBlock, dev);
        static_assert(SMEM_BYTES == 143748, "lut lds size");
        (void)hipFuncSetAttribute((const void*)apply_lut_lds,
                                  hipFuncAttributeMaxDynamicSharedMemorySize, SMEM_BYTES);
        if (max_shm < 0) max_shm = 0;
    }

    if (max_shm >= SMEM_BYTES && ws_size >= (size_t)SMEM_BYTES) {
        // LDS-resident linear u8 table; 256 persistent blocks x 1024 threads
        // (1 block/CU, LDS-capped), sched_barrier-pinned gather/compute phases.
        unsigned int* T = (unsigned int*)d_ws;
        build_lin_u8<<<(LUT_C + 255) / 256, 256, 0, stream>>>(lut, T);
        apply_lut_lds<<<256, 1024, SMEM_BYTES, stream>>>(x, T, out);
    } else {
        __half* T = (__half*)d_ws;
        build_table<<<128, 256, 0, stream>>>(lut, (uint4*)T);
        apply_lut<<<dim3(P_PLANE / (4 * 256), N_IMG), 256, 0, stream>>>(x, T, out);
    }
}